// Round 13
// baseline (149.745 us; speedup 1.0000x reference)
//
#include <hip/hip_runtime.h>

#define N_NODES 10000
#define E_EDGES 160000
#define IN_DIM  512
#define HID_DIM 512
#define OUT_DIM 256
#define MB_T    157   // ceil(10000/64) row tiles

typedef __attribute__((ext_vector_type(8))) short short8;
typedef __attribute__((ext_vector_type(16))) float f32x16;
typedef unsigned short u16;

__device__ __forceinline__ u16 f2bh(float f) {
  union { float f; unsigned u; } v; v.f = f;
  return (u16)((v.u + 0x7FFFu + ((v.u >> 16) & 1u)) >> 16);
}
__device__ __forceinline__ float bh2f(u16 h) {
  union { unsigned u; float f; } v; v.u = ((unsigned)h) << 16;
  return v.f;
}

// tiled layout: chunk c within tile (mb,kt): row=(c>>7)*32+(c&31),
// k=((c>>6)&1)*16+((c>>5)&1)*8 (+0..7). u16 index of chunk start:
__device__ __forceinline__ size_t tidx(int mb, int ktTot, int kt, int c) {
  return ((size_t)(mb * ktTot + kt) * 256 + c) * 8;
}
__device__ __forceinline__ short8 g16(const u16* p) {
  return *reinterpret_cast<const short8*>(p);
}

#define GL_LDS(gsrc, ldst)                                                      \
  __builtin_amdgcn_global_load_lds(                                             \
      (const __attribute__((address_space(1))) unsigned int*)(gsrc),            \
      (__attribute__((address_space(3))) unsigned int*)(ldst), 16, 0, 0)

// ===========================================================================
// scan: exclusive scan of cnt -> row/cursor + dis. shfl-based, 2 barriers.
// ===========================================================================
__global__ __launch_bounds__(1024) void scan_kernel(
    int* __restrict__ cnt, int* __restrict__ row, float* __restrict__ dis) {
  __shared__ int wsum[16];
  const int CH = 10;
  int t = threadIdx.x;
  int lane = t & 63, wid = t >> 6;
  int c[CH], excl[CH];
  int s = 0;
#pragma unroll
  for (int j = 0; j < CH; ++j) {
    int idx = t * CH + j;
    c[j] = (idx < N_NODES) ? cnt[idx] : 0;
    excl[j] = s;
    s += c[j];
  }
  int incl = s;
#pragma unroll
  for (int off = 1; off < 64; off <<= 1) {
    int v = __shfl_up(incl, off);
    if (lane >= off) incl += v;
  }
  if (lane == 63) wsum[wid] = incl;
  __syncthreads();
  if (t < 16) {
    int v = wsum[t];
#pragma unroll
    for (int off = 1; off < 16; off <<= 1) {
      int u = __shfl_up(v, off);
      if (t >= off) v += u;
    }
    wsum[t] = v;
  }
  __syncthreads();
  int waveBase = (wid == 0) ? 0 : wsum[wid - 1];
  int base = waveBase + incl - s;
#pragma unroll
  for (int j = 0; j < CH; ++j) {
    int idx = t * CH + j;
    if (idx < N_NODES) {
      int start = base + excl[j];
      row[idx] = start;
      cnt[idx] = start;
      dis[idx] = rsqrtf((float)c[j] + 1.0f);
    }
  }
  if (t == 1023) row[N_NODES] = wsum[15];
}

// ===========================================================================
// Fused prep kernel (256 threads): pack x, pack f_W, convT, c2, CSR count
// ===========================================================================
#define PREP_PACKX  5000
#define PREP_PACKFW 5256
#define PREP_CONVT  5320
#define PREP_C2END  5336
#define PREP_TOTAL  5961

__device__ __forceinline__ void pack_row(const float* __restrict__ src,
                                         u16* __restrict__ hi, u16* __restrict__ lo,
                                         int i, int tt) {
  int k0 = tt * 4;
  float4 v = *reinterpret_cast<const float4*>(src + (size_t)i * 512 + k0);
  float a[4] = {v.x, v.y, v.z, v.w};
  ushort4 h4, l4;
  u16* hp = &h4.x; u16* lp = &l4.x;
#pragma unroll
  for (int j = 0; j < 4; ++j) {
    u16 hh = f2bh(a[j]);
    hp[j] = hh;
    lp[j] = f2bh(a[j] - bh2f(hh));
  }
  int mb = i >> 6, rl = i & 63;
  int kt = k0 >> 5, si = (k0 >> 4) & 1, kh = (k0 >> 3) & 1;
  int c = (rl >> 5) * 128 + si * 64 + kh * 32 + (rl & 31);
  size_t idx = tidx(mb, 16, kt, c) + (k0 & 7);
  *reinterpret_cast<ushort4*>(hi + idx) = h4;
  *reinterpret_cast<ushort4*>(lo + idx) = l4;
}

__global__ __launch_bounds__(256) void prep_kernel(
    const float* __restrict__ x, const float* __restrict__ f_W,
    const float* __restrict__ gcn_W, const float* __restrict__ f_b,
    const int* __restrict__ dst, int* __restrict__ icnt,
    u16* __restrict__ x_hi, u16* __restrict__ x_lo,
    u16* __restrict__ fWp_hi, u16* __restrict__ fWp_lo,
    u16* __restrict__ Wcomb_hi, u16* __restrict__ Wcomb_lo,
    u16* __restrict__ WbotT_hi, u16* __restrict__ WbotT_lo,
    float* __restrict__ c2) {
  __shared__ float tile[64][65];
  int b = blockIdx.x, t = threadIdx.x;

  if (b < PREP_PACKX) {
    int i = b * 2 + (t >> 7);
    pack_row(x, x_hi, x_lo, i, t & 127);
  } else if (b < PREP_PACKFW) {
    int i = (b - PREP_PACKX) * 2 + (t >> 7);
    pack_row(f_W, fWp_hi, fWp_lo, i, t & 127);
  } else if (b < PREP_CONVT) {
    int lb = b - PREP_PACKFW;
    int part = lb >> 5;
    int li = lb & 31;
    int k0g = (li >> 2) * 64;
    int n0 = (li & 3) * 64;
    const float* W = part ? (gcn_W + (size_t)IN_DIM * OUT_DIM) : gcn_W;
    u16* hi = part ? WbotT_hi : Wcomb_hi;
    u16* lo = part ? WbotT_lo : Wcomb_lo;
    int lk = t >> 4, ln = (t & 15) * 4;
#pragma unroll
    for (int p = 0; p < 4; ++p) {
      float4 v = *reinterpret_cast<const float4*>(W + (size_t)(k0g + p * 16 + lk) * 256 + n0 + ln);
      tile[p * 16 + lk][ln + 0] = v.x;
      tile[p * 16 + lk][ln + 1] = v.y;
      tile[p * 16 + lk][ln + 2] = v.z;
      tile[p * 16 + lk][ln + 3] = v.w;
    }
    __syncthreads();
    int on = t >> 2;
    int ok = (t & 3) * 16;
    int colg = n0 + on;
    int nb = colg >> 6, rl = colg & 63;
#pragma unroll
    for (int q = 0; q < 4; ++q) {
      int kg = k0g + ok + q * 4;
      ushort4 h4, l4;
      u16* hq = &h4.x; u16* lq = &l4.x;
#pragma unroll
      for (int j = 0; j < 4; ++j) {
        float v = tile[ok + q * 4 + j][on];
        u16 hh = f2bh(v);
        hq[j] = hh;
        lq[j] = f2bh(v - bh2f(hh));
      }
      int kt = kg >> 5, si = (kg >> 4) & 1, kh = (kg >> 3) & 1;
      int c = (rl >> 5) * 128 + si * 64 + kh * 32 + (rl & 31);
      size_t idx = tidx(nb, 16, kt, c) + (kg & 7);
      *reinterpret_cast<ushort4*>(hi + idx) = h4;
      *reinterpret_cast<ushort4*>(lo + idx) = l4;
    }
  } else if (b < PREP_C2END) {
    int cb = b - PREP_CONVT;
    float s = 0.f;
    int kb = cb * 32;
#pragma unroll 8
    for (int k = kb; k < kb + 32; ++k)
      s += f_b[k] * gcn_W[(size_t)(IN_DIM + k) * OUT_DIM + t];
    atomicAdd(&c2[t], s);
  } else {
    int e = (b - PREP_C2END) * 256 + t;
    if (e < E_EDGES) atomicAdd(&icnt[dst[e]], 1);
  }
}

// ===========================================================================
// pw_kernel: fused CSR-place + W2 register GEMM (unchanged from round 12)
// ===========================================================================
#define PW_PLACE 625
#define PW_TOTAL 657

__global__ __launch_bounds__(256) void pw_kernel(
    const int* __restrict__ src, const int* __restrict__ dst,
    int* __restrict__ cursor, int* __restrict__ col,
    const u16* __restrict__ WbotT_hi, const u16* __restrict__ WbotT_lo,
    const u16* __restrict__ fWp_hi, const u16* __restrict__ fWp_lo,
    u16* __restrict__ Wcomb_hi, u16* __restrict__ Wcomb_lo) {
  __shared__ u16 H[8192];
  int b = blockIdx.x, t = threadIdx.x;

  if (b < PW_PLACE) {
    int e = b * 256 + t;
    if (e < E_EDGES) {
      int pos = atomicAdd(&cursor[dst[e]], 1);
      col[pos] = src[e];
    }
    return;
  }

  int lb = b - PW_PLACE;
  int nb = lb & 7;
  int mbw = lb >> 3;
  int w = t >> 6, l = t & 63;
  int wr = w >> 1, wc = w & 1;
  int cA = wr * 128 + l;
  int cB = wc * 128 + l;

  f32x16 acc0, acc1;
#pragma unroll
  for (int r = 0; r < 16; ++r) { acc0[r] = 0.f; acc1[r] = 0.f; }

#define W2LOAD(KT, AH0, AL0, BH0, BL0, AH1, AL1, BH1, BL1)                     \
  {                                                                            \
    size_t a0 = tidx(mbw, 16, (KT), cA);                                       \
    size_t a1 = tidx(mbw, 16, (KT), cA + 64);                                  \
    size_t b0 = tidx(nb, 16, (KT), cB);                                        \
    size_t b1 = tidx(nb, 16, (KT), cB + 64);                                   \
    AH0 = g16(WbotT_hi + a0); AL0 = g16(WbotT_lo + a0);                        \
    BH0 = g16(fWp_hi + b0);   BL0 = g16(fWp_lo + b0);                          \
    AH1 = g16(WbotT_hi + a1); AL1 = g16(WbotT_lo + a1);                        \
    BH1 = g16(fWp_hi + b1);   BL1 = g16(fWp_lo + b1);                          \
  }
#define W2MMA(AH0, AL0, BH0, BL0, AH1, AL1, BH1, BL1)                          \
  {                                                                            \
    acc0 = __builtin_amdgcn_mfma_f32_32x32x16_bf16(AH0, BH0, acc0, 0, 0, 0);   \
    acc0 = __builtin_amdgcn_mfma_f32_32x32x16_bf16(AL0, BH0, acc0, 0, 0, 0);   \
    acc0 = __builtin_amdgcn_mfma_f32_32x32x16_bf16(AH0, BL0, acc0, 0, 0, 0);   \
    acc1 = __builtin_amdgcn_mfma_f32_32x32x16_bf16(AH1, BH1, acc1, 0, 0, 0);   \
    acc1 = __builtin_amdgcn_mfma_f32_32x32x16_bf16(AL1, BH1, acc1, 0, 0, 0);   \
    acc1 = __builtin_amdgcn_mfma_f32_32x32x16_bf16(AH1, BL1, acc1, 0, 0, 0);   \
  }

  short8 xah0, xal0, xbh0, xbl0, xah1, xal1, xbh1, xbl1;
  short8 yah0, yal0, ybh0, ybl0, yah1, yal1, ybh1, ybl1;
  W2LOAD(0, xah0, xal0, xbh0, xbl0, xah1, xal1, xbh1, xbl1)
#pragma unroll
  for (int kt = 0; kt < 16; kt += 2) {
    W2LOAD(kt + 1, yah0, yal0, ybh0, ybl0, yah1, yal1, ybh1, ybl1)
    W2MMA(xah0, xal0, xbh0, xbl0, xah1, xal1, xbh1, xbl1)
    if (kt + 2 < 16)
      W2LOAD(kt + 2, xah0, xal0, xbh0, xbl0, xah1, xal1, xbh1, xbl1)
    W2MMA(yah0, yal0, ybh0, ybl0, yah1, yal1, ybh1, ybl1)
  }
#undef W2LOAD
#undef W2MMA

  f32x16 acc = acc0 + acc1;
  u16* Hhi = H;
  u16* Hlo = H + 4096;
  int r0l = wr * 32 + 4 * (l >> 5);
  int c0l = wc * 32 + (l & 31);
#pragma unroll
  for (int r = 0; r < 16; ++r) {
    int rl = r0l + (r & 3) + 8 * (r >> 2);
    float v = acc[r];
    u16 hh = f2bh(v);
    Hhi[rl * 64 + c0l] = hh;
    Hlo[rl * 64 + c0l] = f2bh(v - bh2f(hh));
  }
  __syncthreads();
#pragma unroll
  for (int pl = 0; pl < 2; ++pl) {
    const u16* Hs = pl ? Hlo : Hhi;
    u16* dA = pl ? Wcomb_lo : Wcomb_hi;
#pragma unroll
    for (int j = 0; j < 2; ++j) {
      int ci = t + j * 256;
      int ktl = ci >> 8;
      int c = ci & 255;
      int r = ((c >> 7) & 1) * 32 + (c & 31);
      int kloc = ktl * 32 + ((c >> 6) & 1) * 16 + ((c >> 5) & 1) * 8;
      short8 v = *reinterpret_cast<const short8*>(Hs + r * 64 + kloc);
      size_t db = tidx(mbw + 4, 16, nb * 2 + ktl, c);
      *reinterpret_cast<short8*>(dA + db) = v;
    }
  }
}

// ===========================================================================
// Z-GEMM: Z = x @ Wcomb. Epilogue: cols<256 -> z1 fp32; cols 256-383 -> z2A
// bf16; cols 384-511 -> z2B bf16 (split 2.56MB tables for L2 residency).
// ===========================================================================
template <int NB>
__global__ __launch_bounds__(256) void zgemm_kernel(
    const u16* __restrict__ Ah, const u16* __restrict__ Al,
    const u16* __restrict__ Bh, const u16* __restrict__ Bl,
    float* __restrict__ z1, u16* __restrict__ z2A, u16* __restrict__ z2B,
    int M, int K) {
  constexpr int BCH = NB * 256;
  __shared__ short8 S[2][512 + 2 * BCH];

  int bid = blockIdx.x;
  int X = bid & 7, sslot = bid >> 3;
  int mb = X + 8 * (sslot >> 2);
  int nbB = sslot & 3;
  if (mb >= MB_T) return;

  int t = threadIdx.x, w = t >> 6, l = t & 63;
  int wr = w >> 1, wc = w & 1;
  int cid = t;
  int ktTot = K >> 5;

  f32x16 acc[NB][2];
#pragma unroll
  for (int n = 0; n < NB; ++n)
#pragma unroll
    for (int si = 0; si < 2; ++si)
#pragma unroll
      for (int r = 0; r < 16; ++r) acc[n][si][r] = 0.f;

  int nt = K / 32;

#define ZSTAGE(BUF, K0)                                                        \
  {                                                                            \
    size_t ab = tidx(mb, ktTot, (K0) >> 5, cid);                               \
    short8* base = &S[BUF][0] + w * 64;                                        \
    GL_LDS(Ah + ab, base);                                                     \
    GL_LDS(Al + ab, base + 256);                                               \
    _Pragma("unroll") for (int j = 0; j < NB; ++j) {                           \
      size_t bb = tidx(nbB * NB + j, ktTot, (K0) >> 5, cid);                   \
      GL_LDS(Bh + bb, base + 512 + j * 256);                                   \
      GL_LDS(Bl + bb, base + 512 + BCH + j * 256);                             \
    }                                                                          \
  }

  ZSTAGE(0, 0)
  for (int ti = 0; ti < nt; ++ti) {
    int b = ti & 1;
    __syncthreads();
    if (ti + 1 < nt) ZSTAGE(b ^ 1, (ti + 1) * 32)
#pragma unroll
    for (int si = 0; si < 2; ++si) {
      short8 ah = S[b][wr * 128 + si * 64 + l];
      short8 al = S[b][256 + wr * 128 + si * 64 + l];
#pragma unroll
      for (int n2 = 0; n2 < NB; ++n2) {
        short8 bh = S[b][512 + wc * 256 + n2 * 128 + si * 64 + l];
        short8 bl = S[b][512 + BCH + wc * 256 + n2 * 128 + si * 64 + l];
        acc[n2][si] = __builtin_amdgcn_mfma_f32_32x32x16_bf16(ah, bh, acc[n2][si], 0, 0, 0);
        acc[n2][si] = __builtin_amdgcn_mfma_f32_32x32x16_bf16(al, bh, acc[n2][si], 0, 0, 0);
        acc[n2][si] = __builtin_amdgcn_mfma_f32_32x32x16_bf16(ah, bl, acc[n2][si], 0, 0, 0);
      }
    }
  }
#undef ZSTAGE

  int r0 = mb * 64 + wr * 32 + 4 * (l >> 5);
#pragma unroll
  for (int n2 = 0; n2 < NB; ++n2) {
    f32x16 a = acc[n2][0] + acc[n2][1];
    int colg = nbB * (NB * 64) + wc * 64 + n2 * 32 + (l & 31);
#pragma unroll
    for (int r = 0; r < 16; ++r) {
      int rowg = r0 + (r & 3) + 8 * (r >> 2);
      if (rowg < M) {
        float v = a[r];
        if (colg < 256) {
          z1[(size_t)rowg * 256 + colg] = v;
        } else {
          int cg = colg - 256;
          u16* dp = (cg < 128) ? z2A : z2B;
          dp[(size_t)rowg * 128 + (cg & 127)] = f2bh(v);
        }
      }
    }
  }
}

// ===========================================================================
// h_build: h[i] = z1[i] + sum_{j in N(i)} z2[j] + c2.  2 nodes/block,
// 2 phases (col halves) so each gather table is 2.56MB = per-XCD-L2-resident.
// 16 lanes/edge, 4 edges/wave, 4-way unroll. Writes h fp32 + split bf16.
// ===========================================================================
__global__ __launch_bounds__(128) void h_build_kernel(
    const float* __restrict__ z1, const u16* __restrict__ z2A,
    const u16* __restrict__ z2B, const int* __restrict__ row,
    const int* __restrict__ col, const float* __restrict__ c2,
    float* __restrict__ h, u16* __restrict__ hbA, u16* __restrict__ hbB) {
  int i = blockIdx.x * 2 + (threadIdx.x >> 6);
  int t = threadIdx.x & 63;
  int q = t >> 4, sl = t & 15;
  int beg = row[i], end = row[i + 1];

#pragma unroll
  for (int half = 0; half < 2; ++half) {
    const u16* z2 = half ? z2B : z2A;
    u16* hb = half ? hbB : hbA;
    float a0[8] = {}, a1[8] = {}, a2[8] = {}, a3[8] = {};
    int e = beg + q;
    for (; e + 12 < end; e += 16) {
      int s0 = col[e], s1 = col[e + 4], s2 = col[e + 8], s3 = col[e + 12];
      short8 v0 = g16(z2 + (size_t)s0 * 128 + sl * 8);
      short8 v1 = g16(z2 + (size_t)s1 * 128 + sl * 8);
      short8 v2 = g16(z2 + (size_t)s2 * 128 + sl * 8);
      short8 v3 = g16(z2 + (size_t)s3 * 128 + sl * 8);
#pragma unroll
      for (int j = 0; j < 8; ++j) {
        a0[j] += bh2f((u16)v0[j]);
        a1[j] += bh2f((u16)v1[j]);
        a2[j] += bh2f((u16)v2[j]);
        a3[j] += bh2f((u16)v3[j]);
      }
    }
    for (; e < end; e += 4) {
      int s = col[e];
      short8 v = g16(z2 + (size_t)s * 128 + sl * 8);
#pragma unroll
      for (int j = 0; j < 8; ++j) a0[j] += bh2f((u16)v[j]);
    }
    float acc[8];
#pragma unroll
    for (int j = 0; j < 8; ++j) {
      acc[j] = a0[j] + a1[j] + a2[j] + a3[j];
      acc[j] += __shfl_xor(acc[j], 16);
      acc[j] += __shfl_xor(acc[j], 32);
    }
    if (t < 16) {
      size_t base = (size_t)i * 256 + half * 128 + sl * 8;
      float4 za = *reinterpret_cast<const float4*>(z1 + base);
      float4 zb = *reinterpret_cast<const float4*>(z1 + base + 4);
      float4 ca = *reinterpret_cast<const float4*>(c2 + half * 128 + sl * 8);
      float4 cb = *reinterpret_cast<const float4*>(c2 + half * 128 + sl * 8 + 4);
      float hv[8] = {za.x + ca.x + acc[0], za.y + ca.y + acc[1],
                     za.z + ca.z + acc[2], za.w + ca.w + acc[3],
                     zb.x + cb.x + acc[4], zb.y + cb.y + acc[5],
                     zb.z + cb.z + acc[6], zb.w + cb.w + acc[7]};
      float4 o0{hv[0], hv[1], hv[2], hv[3]};
      float4 o1{hv[4], hv[5], hv[6], hv[7]};
      *reinterpret_cast<float4*>(h + base) = o0;
      *reinterpret_cast<float4*>(h + base + 4) = o1;
      short8 hb8;
#pragma unroll
      for (int j = 0; j < 8; ++j) hb8[j] = (short)f2bh(hv[j]);
      *reinterpret_cast<short8*>(hb + (size_t)i * 128 + sl * 8) = hb8;
    }
  }
}

// ===========================================================================
// GCN gather: out[i] = dis_i*sum dis_j h_j (split bf16) + dis_i^2 h_i(fp32) + b
// same 2-phase / 16-lane-per-edge structure.
// ===========================================================================
__global__ __launch_bounds__(128) void gcn_gather_kernel(
    const float* __restrict__ h, const u16* __restrict__ hbA,
    const u16* __restrict__ hbB, const int* __restrict__ row,
    const int* __restrict__ col, const float* __restrict__ dis,
    const float* __restrict__ gcn_b, float* __restrict__ outg) {
  int i = blockIdx.x * 2 + (threadIdx.x >> 6);
  int t = threadIdx.x & 63;
  int q = t >> 4, sl = t & 15;
  int beg = row[i], end = row[i + 1];
  float di = dis[i];

#pragma unroll
  for (int half = 0; half < 2; ++half) {
    const u16* hb = half ? hbB : hbA;
    float a0[8] = {}, a1[8] = {}, a2[8] = {}, a3[8] = {};
    int e = beg + q;
    for (; e + 12 < end; e += 16) {
      int s0 = col[e], s1 = col[e + 4], s2 = col[e + 8], s3 = col[e + 12];
      float w0 = dis[s0], w1 = dis[s1], w2 = dis[s2], w3 = dis[s3];
      short8 v0 = g16(hb + (size_t)s0 * 128 + sl * 8);
      short8 v1 = g16(hb + (size_t)s1 * 128 + sl * 8);
      short8 v2 = g16(hb + (size_t)s2 * 128 + sl * 8);
      short8 v3 = g16(hb + (size_t)s3 * 128 + sl * 8);
#pragma unroll
      for (int j = 0; j < 8; ++j) {
        a0[j] += w0 * bh2f((u16)v0[j]);
        a1[j] += w1 * bh2f((u16)v1[j]);
        a2[j] += w2 * bh2f((u16)v2[j]);
        a3[j] += w3 * bh2f((u16)v3[j]);
      }
    }
    for (; e < end; e += 4) {
      int s = col[e];
      float wv = dis[s];
      short8 v = g16(hb + (size_t)s * 128 + sl * 8);
#pragma unroll
      for (int j = 0; j < 8; ++j) a0[j] += wv * bh2f((u16)v[j]);
    }
    float acc[8];
#pragma unroll
    for (int j = 0; j < 8; ++j) {
      acc[j] = a0[j] + a1[j] + a2[j] + a3[j];
      acc[j] += __shfl_xor(acc[j], 16);
      acc[j] += __shfl_xor(acc[j], 32);
    }
    if (t < 16) {
      size_t base = (size_t)i * 256 + half * 128 + sl * 8;
      float4 ha = *reinterpret_cast<const float4*>(h + base);
      float4 hb4 = *reinterpret_cast<const float4*>(h + base + 4);
      float4 ba = *reinterpret_cast<const float4*>(gcn_b + half * 128 + sl * 8);
      float4 bb = *reinterpret_cast<const float4*>(gcn_b + half * 128 + sl * 8 + 4);
      float self = di * di;
      float4 o0{di * acc[0] + self * ha.x + ba.x, di * acc[1] + self * ha.y + ba.y,
                di * acc[2] + self * ha.z + ba.z, di * acc[3] + self * ha.w + ba.w};
      float4 o1{di * acc[4] + self * hb4.x + bb.x, di * acc[5] + self * hb4.y + bb.y,
                di * acc[6] + self * hb4.z + bb.z, di * acc[7] + self * hb4.w + bb.w};
      *reinterpret_cast<float4*>(outg + base) = o0;
      *reinterpret_cast<float4*>(outg + base + 4) = o1;
    }
  }
}

// ===========================================================================
// decode MLP: 8 nodes per block
// ===========================================================================
#define DEC_NODES 8
__global__ __launch_bounds__(128) void decode_kernel(
    const float* __restrict__ outg, const float* __restrict__ d1_W,
    const float* __restrict__ d1_b, const float* __restrict__ d2_W,
    const float* __restrict__ d2_b, float* __restrict__ z1) {
  __shared__ float rows[DEC_NODES][OUT_DIM];
  __shared__ float s0[128], s1[128];
  int t = threadIdx.x;
  int n0 = blockIdx.x * DEC_NODES;
#pragma unroll
  for (int j = 0; j < 4; ++j) {
    int idx = j * 512 + t * 4;
    *reinterpret_cast<float4*>(&rows[0][idx]) =
        *reinterpret_cast<const float4*>(outg + (size_t)n0 * OUT_DIM + idx);
  }
  __syncthreads();
  float acc[DEC_NODES];
  float b1 = d1_b[t];
#pragma unroll
  for (int n = 0; n < DEC_NODES; ++n) acc[n] = b1;
#pragma unroll 4
  for (int k = 0; k < OUT_DIM; ++k) {
    float wv = d1_W[k * 128 + t];
#pragma unroll
    for (int n = 0; n < DEC_NODES; ++n) acc[n] += rows[n][k] * wv;
  }
  float w0 = d2_W[t * 2 + 0], w1 = d2_W[t * 2 + 1];
  for (int n = 0; n < DEC_NODES; ++n) {
    float a = fmaxf(acc[n], 0.f);
    s0[t] = a * w0;
    s1[t] = a * w1;
    __syncthreads();
    for (int off = 64; off > 0; off >>= 1) {
      if (t < off) {
        s0[t] += s0[t + off];
        s1[t] += s1[t + off];
      }
      __syncthreads();
    }
    if (t == 0) {
      z1[(size_t)(n0 + n) * 2 + 0] = s0[0] + d2_b[0];
      z1[(size_t)(n0 + n) * 2 + 1] = s1[0] + d2_b[1];
    }
    __syncthreads();
  }
}

// ===========================================================================
extern "C" void kernel_launch(void* const* d_in, const int* in_sizes, int n_in,
                              void* d_out, int out_size, void* d_ws, size_t ws_size,
                              hipStream_t stream) {
  const float* x     = (const float*)d_in[0];
  const int*   edge  = (const int*)d_in[1];
  const float* f_W   = (const float*)d_in[2];
  const float* f_b   = (const float*)d_in[3];
  const float* gcn_W = (const float*)d_in[4];
  const float* gcn_b = (const float*)d_in[5];
  const float* d1_W  = (const float*)d_in[6];
  const float* d1_b  = (const float*)d_in[7];
  const float* d2_W  = (const float*)d_in[8];
  const float* d2_b  = (const float*)d_in[9];
  float* out = (float*)d_out;
  char*  wsb = (char*)d_ws;

  const int* src = edge;
  const int* dst = edge + E_EDGES;

  // -------- v9 layout (bytes) --------
  const size_t TS   = (size_t)MB_T * 16 * 256 * 8 * sizeof(u16);
  const size_t WTLE = (size_t)16 * 256 * 8 * sizeof(u16);

  size_t o = 0;
  u16*   x_hi = (u16*)(wsb + o); o += TS;
  u16*   x_lo = (u16*)(wsb + o); o += TS;
  float* z1   = (float*)(wsb + o); o += (size_t)N_NODES * 256 * 4;
  u16*   z2A  = (u16*)(wsb + o);   o += (size_t)N_NODES * 128 * 2;
  u16*   z2B  = (u16*)(wsb + o);   o += (size_t)N_NODES * 128 * 2;
  float* h    = (float*)(wsb + o); o += (size_t)N_NODES * 256 * 4;
  u16*   hbA  = (u16*)(wsb + o);   o += (size_t)N_NODES * 128 * 2;
  u16*   hbB  = (u16*)(wsb + o);   o += (size_t)N_NODES * 128 * 2;
  float* dis9 = (float*)(wsb + o); o += (size_t)N_NODES * 4;
  int*   icnt9 = (int*)(wsb + o);  o += (size_t)N_NODES * 4;
  float* c2   = (float*)(wsb + o); o += OUT_DIM * 4;   // adjacent to icnt9
  int*   irow9 = (int*)(wsb + o);  o += (size_t)(N_NODES + 1) * 4 + 12;
  int*   icol9 = (int*)(wsb + o);  o += (size_t)E_EDGES * 4;
  u16*   Wcomb_hi = (u16*)(wsb + o); o += 8 * WTLE;
  u16*   Wcomb_lo = (u16*)(wsb + o); o += 8 * WTLE;
  u16*   WbotT_hi = (u16*)(wsb + o); o += 4 * WTLE;
  u16*   WbotT_lo = (u16*)(wsb + o); o += 4 * WTLE;
  u16*   fWp_hi   = (u16*)(wsb + o); o += 8 * WTLE;
  u16*   fWp_lo   = (u16*)(wsb + o); o += 8 * WTLE;
  float* outg = (float*)(wsb + 0);  // overlays x_hi (dead after Z-GEMM)
  const size_t v9_needed = o;

  if (ws_size >= v9_needed) {
    // ---- memset covers icnt9 + c2 (contiguous)
    hipMemsetAsync(icnt9, 0, (size_t)N_NODES * sizeof(int) + OUT_DIM * sizeof(float), stream);

    // ---- fused prep (pack x, pack f_W, convT, c2, CSR count)
    prep_kernel<<<PREP_TOTAL, 256, 0, stream>>>(
        x, f_W, gcn_W, f_b, dst, icnt9, x_hi, x_lo, fWp_hi, fWp_lo,
        Wcomb_hi, Wcomb_lo, WbotT_hi, WbotT_lo, c2);

    // ---- scan
    scan_kernel<<<1, 1024, 0, stream>>>(icnt9, irow9, dis9);

    // ---- fused place + W2 register GEMM
    pw_kernel<<<PW_TOTAL, 256, 0, stream>>>(
        src, dst, icnt9, icol9, WbotT_hi, WbotT_lo, fWp_hi, fWp_lo,
        Wcomb_hi, Wcomb_lo);

    // ---- Z = x @ [Wtop | W2] : z1 fp32, z2 split bf16
    zgemm_kernel<2><<<640, 256, 0, stream>>>(
        x_hi, x_lo, Wcomb_hi, Wcomb_lo, z1, z2A, z2B, N_NODES, IN_DIM);

    // ---- h = z1 + gather(z2) + c2 (2-phase split gather)
    h_build_kernel<<<N_NODES / 2, 128, 0, stream>>>(
        z1, z2A, z2B, irow9, icol9, c2, h, hbA, hbB);

    // ---- GCN gather (2-phase split) + decode
    gcn_gather_kernel<<<N_NODES / 2, 128, 0, stream>>>(
        h, hbA, hbB, irow9, icol9, dis9, gcn_b, outg);
    decode_kernel<<<N_NODES / DEC_NODES, 128, 0, stream>>>(
        outg, d1_W, d1_b, d2_W, d2_b, out);
  }
}

// Round 14
// 140.351 us; speedup vs baseline: 1.0669x; 1.0669x over previous
//
#include <hip/hip_runtime.h>

#define N_NODES 10000
#define E_EDGES 160000
#define IN_DIM  512
#define HID_DIM 512
#define OUT_DIM 256
#define MB_T    157   // ceil(10000/64) row tiles

typedef __attribute__((ext_vector_type(8))) short short8;
typedef __attribute__((ext_vector_type(16))) float f32x16;
typedef unsigned short u16;

__device__ __forceinline__ u16 f2bh(float f) {
  union { float f; unsigned u; } v; v.f = f;
  return (u16)((v.u + 0x7FFFu + ((v.u >> 16) & 1u)) >> 16);
}
__device__ __forceinline__ float bh2f(u16 h) {
  union { unsigned u; float f; } v; v.u = ((unsigned)h) << 16;
  return v.f;
}

// tiled layout: chunk c within tile (mb,kt): row=(c>>7)*32+(c&31),
// k=((c>>6)&1)*16+((c>>5)&1)*8 (+0..7). u16 index of chunk start:
__device__ __forceinline__ size_t tidx(int mb, int ktTot, int kt, int c) {
  return ((size_t)(mb * ktTot + kt) * 256 + c) * 8;
}
__device__ __forceinline__ short8 g16(const u16* p) {
  return *reinterpret_cast<const short8*>(p);
}

#define GL_LDS(gsrc, ldst)                                                      \
  __builtin_amdgcn_global_load_lds(                                             \
      (const __attribute__((address_space(1))) unsigned int*)(gsrc),            \
      (__attribute__((address_space(3))) unsigned int*)(ldst), 16, 0, 0)

// ===========================================================================
// scan: exclusive scan of cnt -> row/cursor + dis. shfl-based, 2 barriers.
// ===========================================================================
__global__ __launch_bounds__(1024) void scan_kernel(
    int* __restrict__ cnt, int* __restrict__ row, float* __restrict__ dis) {
  __shared__ int wsum[16];
  const int CH = 10;
  int t = threadIdx.x;
  int lane = t & 63, wid = t >> 6;
  int c[CH], excl[CH];
  int s = 0;
#pragma unroll
  for (int j = 0; j < CH; ++j) {
    int idx = t * CH + j;
    c[j] = (idx < N_NODES) ? cnt[idx] : 0;
    excl[j] = s;
    s += c[j];
  }
  int incl = s;
#pragma unroll
  for (int off = 1; off < 64; off <<= 1) {
    int v = __shfl_up(incl, off);
    if (lane >= off) incl += v;
  }
  if (lane == 63) wsum[wid] = incl;
  __syncthreads();
  if (t < 16) {
    int v = wsum[t];
#pragma unroll
    for (int off = 1; off < 16; off <<= 1) {
      int u = __shfl_up(v, off);
      if (t >= off) v += u;
    }
    wsum[t] = v;
  }
  __syncthreads();
  int waveBase = (wid == 0) ? 0 : wsum[wid - 1];
  int base = waveBase + incl - s;
#pragma unroll
  for (int j = 0; j < CH; ++j) {
    int idx = t * CH + j;
    if (idx < N_NODES) {
      int start = base + excl[j];
      row[idx] = start;
      cnt[idx] = start;
      dis[idx] = rsqrtf((float)c[j] + 1.0f);
    }
  }
  if (t == 1023) row[N_NODES] = wsum[15];
}

// ===========================================================================
// Fused prep kernel (256 threads):
//  [0,2500)      : pack x, 4 rows/block, 1 chunk (16B) per thread
//  [2500,2628)   : pack f_W, 4 rows/block
//  [2628,2692)   : convT Wtop / Wbot
//  [2692,2708)   : c2 partials
//  [2708,3333)   : CSR count
// ===========================================================================
#define PREP_PACKX  2500
#define PREP_PACKFW 2628
#define PREP_CONVT  2692
#define PREP_C2END  2708
#define PREP_TOTAL  3333

// thread tt in [0,64): packs k = tt*8 .. tt*8+7 of row i -> one 16B chunk
__device__ __forceinline__ void pack_row8(const float* __restrict__ src,
                                          u16* __restrict__ hi, u16* __restrict__ lo,
                                          int i, int tt) {
  int k0 = tt * 8;
  const float* p = src + (size_t)i * 512 + k0;
  float4 u0 = *reinterpret_cast<const float4*>(p);
  float4 u1 = *reinterpret_cast<const float4*>(p + 4);
  float a[8] = {u0.x, u0.y, u0.z, u0.w, u1.x, u1.y, u1.z, u1.w};
  short8 h8, l8;
#pragma unroll
  for (int j = 0; j < 8; ++j) {
    u16 hh = f2bh(a[j]);
    h8[j] = (short)hh;
    l8[j] = (short)f2bh(a[j] - bh2f(hh));
  }
  int mb = i >> 6, rl = i & 63;
  int kt = k0 >> 5, si = (k0 >> 4) & 1, kh = (k0 >> 3) & 1;
  int c = (rl >> 5) * 128 + si * 64 + kh * 32 + (rl & 31);
  size_t idx = tidx(mb, 16, kt, c);
  *reinterpret_cast<short8*>(hi + idx) = h8;
  *reinterpret_cast<short8*>(lo + idx) = l8;
}

__global__ __launch_bounds__(256) void prep_kernel(
    const float* __restrict__ x, const float* __restrict__ f_W,
    const float* __restrict__ gcn_W, const float* __restrict__ f_b,
    const int* __restrict__ dst, int* __restrict__ icnt,
    u16* __restrict__ x_hi, u16* __restrict__ x_lo,
    u16* __restrict__ fWp_hi, u16* __restrict__ fWp_lo,
    u16* __restrict__ Wcomb_hi, u16* __restrict__ Wcomb_lo,
    u16* __restrict__ WbotT_hi, u16* __restrict__ WbotT_lo,
    float* __restrict__ c2) {
  __shared__ float tile[64][65];
  int b = blockIdx.x, t = threadIdx.x;

  if (b < PREP_PACKX) {
    int i = b * 4 + (t >> 6);
    pack_row8(x, x_hi, x_lo, i, t & 63);
  } else if (b < PREP_PACKFW) {
    int i = (b - PREP_PACKX) * 4 + (t >> 6);
    pack_row8(f_W, fWp_hi, fWp_lo, i, t & 63);
  } else if (b < PREP_CONVT) {
    int lb = b - PREP_PACKFW;
    int part = lb >> 5;
    int li = lb & 31;
    int k0g = (li >> 2) * 64;
    int n0 = (li & 3) * 64;
    const float* W = part ? (gcn_W + (size_t)IN_DIM * OUT_DIM) : gcn_W;
    u16* hi = part ? WbotT_hi : Wcomb_hi;
    u16* lo = part ? WbotT_lo : Wcomb_lo;
    int lk = t >> 4, ln = (t & 15) * 4;
#pragma unroll
    for (int p = 0; p < 4; ++p) {
      float4 v = *reinterpret_cast<const float4*>(W + (size_t)(k0g + p * 16 + lk) * 256 + n0 + ln);
      tile[p * 16 + lk][ln + 0] = v.x;
      tile[p * 16 + lk][ln + 1] = v.y;
      tile[p * 16 + lk][ln + 2] = v.z;
      tile[p * 16 + lk][ln + 3] = v.w;
    }
    __syncthreads();
    int on = t >> 2;
    int ok = (t & 3) * 16;
    int colg = n0 + on;
    int nb = colg >> 6, rl = colg & 63;
#pragma unroll
    for (int q = 0; q < 4; ++q) {
      int kg = k0g + ok + q * 4;
      ushort4 h4, l4;
      u16* hq = &h4.x; u16* lq = &l4.x;
#pragma unroll
      for (int j = 0; j < 4; ++j) {
        float v = tile[ok + q * 4 + j][on];
        u16 hh = f2bh(v);
        hq[j] = hh;
        lq[j] = f2bh(v - bh2f(hh));
      }
      int kt = kg >> 5, si = (kg >> 4) & 1, kh = (kg >> 3) & 1;
      int c = (rl >> 5) * 128 + si * 64 + kh * 32 + (rl & 31);
      size_t idx = tidx(nb, 16, kt, c) + (kg & 7);
      *reinterpret_cast<ushort4*>(hi + idx) = h4;
      *reinterpret_cast<ushort4*>(lo + idx) = l4;
    }
  } else if (b < PREP_C2END) {
    int cb = b - PREP_CONVT;
    float s = 0.f;
    int kb = cb * 32;
#pragma unroll 8
    for (int k = kb; k < kb + 32; ++k)
      s += f_b[k] * gcn_W[(size_t)(IN_DIM + k) * OUT_DIM + t];
    atomicAdd(&c2[t], s);
  } else {
    int e = (b - PREP_C2END) * 256 + t;
    if (e < E_EDGES) atomicAdd(&icnt[dst[e]], 1);
  }
}

// ===========================================================================
// pw_kernel: fused CSR-place + W2 register GEMM
// ===========================================================================
#define PW_PLACE 625
#define PW_TOTAL 657

__global__ __launch_bounds__(256) void pw_kernel(
    const int* __restrict__ src, const int* __restrict__ dst,
    int* __restrict__ cursor, int* __restrict__ col,
    const u16* __restrict__ WbotT_hi, const u16* __restrict__ WbotT_lo,
    const u16* __restrict__ fWp_hi, const u16* __restrict__ fWp_lo,
    u16* __restrict__ Wcomb_hi, u16* __restrict__ Wcomb_lo) {
  __shared__ u16 H[8192];
  int b = blockIdx.x, t = threadIdx.x;

  if (b < PW_PLACE) {
    int e = b * 256 + t;
    if (e < E_EDGES) {
      int pos = atomicAdd(&cursor[dst[e]], 1);
      col[pos] = src[e];
    }
    return;
  }

  int lb = b - PW_PLACE;
  int nb = lb & 7;
  int mbw = lb >> 3;
  int w = t >> 6, l = t & 63;
  int wr = w >> 1, wc = w & 1;
  int cA = wr * 128 + l;
  int cB = wc * 128 + l;

  f32x16 acc0, acc1;
#pragma unroll
  for (int r = 0; r < 16; ++r) { acc0[r] = 0.f; acc1[r] = 0.f; }

#define W2LOAD(KT, AH0, AL0, BH0, BL0, AH1, AL1, BH1, BL1)                     \
  {                                                                            \
    size_t a0 = tidx(mbw, 16, (KT), cA);                                       \
    size_t a1 = tidx(mbw, 16, (KT), cA + 64);                                  \
    size_t b0 = tidx(nb, 16, (KT), cB);                                        \
    size_t b1 = tidx(nb, 16, (KT), cB + 64);                                   \
    AH0 = g16(WbotT_hi + a0); AL0 = g16(WbotT_lo + a0);                        \
    BH0 = g16(fWp_hi + b0);   BL0 = g16(fWp_lo + b0);                          \
    AH1 = g16(WbotT_hi + a1); AL1 = g16(WbotT_lo + a1);                        \
    BH1 = g16(fWp_hi + b1);   BL1 = g16(fWp_lo + b1);                          \
  }
#define W2MMA(AH0, AL0, BH0, BL0, AH1, AL1, BH1, BL1)                          \
  {                                                                            \
    acc0 = __builtin_amdgcn_mfma_f32_32x32x16_bf16(AH0, BH0, acc0, 0, 0, 0);   \
    acc0 = __builtin_amdgcn_mfma_f32_32x32x16_bf16(AL0, BH0, acc0, 0, 0, 0);   \
    acc0 = __builtin_amdgcn_mfma_f32_32x32x16_bf16(AH0, BL0, acc0, 0, 0, 0);   \
    acc1 = __builtin_amdgcn_mfma_f32_32x32x16_bf16(AH1, BH1, acc1, 0, 0, 0);   \
    acc1 = __builtin_amdgcn_mfma_f32_32x32x16_bf16(AL1, BH1, acc1, 0, 0, 0);   \
    acc1 = __builtin_amdgcn_mfma_f32_32x32x16_bf16(AH1, BL1, acc1, 0, 0, 0);   \
  }

  short8 xah0, xal0, xbh0, xbl0, xah1, xal1, xbh1, xbl1;
  short8 yah0, yal0, ybh0, ybl0, yah1, yal1, ybh1, ybl1;
  W2LOAD(0, xah0, xal0, xbh0, xbl0, xah1, xal1, xbh1, xbl1)
#pragma unroll
  for (int kt = 0; kt < 16; kt += 2) {
    W2LOAD(kt + 1, yah0, yal0, ybh0, ybl0, yah1, yal1, ybh1, ybl1)
    W2MMA(xah0, xal0, xbh0, xbl0, xah1, xal1, xbh1, xbl1)
    if (kt + 2 < 16)
      W2LOAD(kt + 2, xah0, xal0, xbh0, xbl0, xah1, xal1, xbh1, xbl1)
    W2MMA(yah0, yal0, ybh0, ybl0, yah1, yal1, ybh1, ybl1)
  }
#undef W2LOAD
#undef W2MMA

  f32x16 acc = acc0 + acc1;
  u16* Hhi = H;
  u16* Hlo = H + 4096;
  int r0l = wr * 32 + 4 * (l >> 5);
  int c0l = wc * 32 + (l & 31);
#pragma unroll
  for (int r = 0; r < 16; ++r) {
    int rl = r0l + (r & 3) + 8 * (r >> 2);
    float v = acc[r];
    u16 hh = f2bh(v);
    Hhi[rl * 64 + c0l] = hh;
    Hlo[rl * 64 + c0l] = f2bh(v - bh2f(hh));
  }
  __syncthreads();
#pragma unroll
  for (int pl = 0; pl < 2; ++pl) {
    const u16* Hs = pl ? Hlo : Hhi;
    u16* dA = pl ? Wcomb_lo : Wcomb_hi;
#pragma unroll
    for (int j = 0; j < 2; ++j) {
      int ci = t + j * 256;
      int ktl = ci >> 8;
      int c = ci & 255;
      int r = ((c >> 7) & 1) * 32 + (c & 31);
      int kloc = ktl * 32 + ((c >> 6) & 1) * 16 + ((c >> 5) & 1) * 8;
      short8 v = *reinterpret_cast<const short8*>(Hs + r * 64 + kloc);
      size_t db = tidx(mbw + 4, 16, nb * 2 + ktl, c);
      *reinterpret_cast<short8*>(dA + db) = v;
    }
  }
}

// ===========================================================================
// Z-GEMM: Z = x @ Wcomb. XCD-aware remap. z1 fp32, z2 bf16.
// ===========================================================================
template <int NB>
__global__ __launch_bounds__(256) void zgemm_kernel(
    const u16* __restrict__ Ah, const u16* __restrict__ Al,
    const u16* __restrict__ Bh, const u16* __restrict__ Bl,
    float* __restrict__ z1, u16* __restrict__ z2b, int M, int K) {
  constexpr int BCH = NB * 256;
  __shared__ short8 S[2][512 + 2 * BCH];

  int bid = blockIdx.x;
  int X = bid & 7, sslot = bid >> 3;
  int mb = X + 8 * (sslot >> 2);
  int nbB = sslot & 3;
  if (mb >= MB_T) return;

  int t = threadIdx.x, w = t >> 6, l = t & 63;
  int wr = w >> 1, wc = w & 1;
  int cid = t;
  int ktTot = K >> 5;

  f32x16 acc[NB][2];
#pragma unroll
  for (int n = 0; n < NB; ++n)
#pragma unroll
    for (int si = 0; si < 2; ++si)
#pragma unroll
      for (int r = 0; r < 16; ++r) acc[n][si][r] = 0.f;

  int nt = K / 32;

#define ZSTAGE(BUF, K0)                                                        \
  {                                                                            \
    size_t ab = tidx(mb, ktTot, (K0) >> 5, cid);                               \
    short8* base = &S[BUF][0] + w * 64;                                        \
    GL_LDS(Ah + ab, base);                                                     \
    GL_LDS(Al + ab, base + 256);                                               \
    _Pragma("unroll") for (int j = 0; j < NB; ++j) {                           \
      size_t bb = tidx(nbB * NB + j, ktTot, (K0) >> 5, cid);                   \
      GL_LDS(Bh + bb, base + 512 + j * 256);                                   \
      GL_LDS(Bl + bb, base + 512 + BCH + j * 256);                             \
    }                                                                          \
  }

  ZSTAGE(0, 0)
  for (int ti = 0; ti < nt; ++ti) {
    int b = ti & 1;
    __syncthreads();
    if (ti + 1 < nt) ZSTAGE(b ^ 1, (ti + 1) * 32)
#pragma unroll
    for (int si = 0; si < 2; ++si) {
      short8 ah = S[b][wr * 128 + si * 64 + l];
      short8 al = S[b][256 + wr * 128 + si * 64 + l];
#pragma unroll
      for (int n2 = 0; n2 < NB; ++n2) {
        short8 bh = S[b][512 + wc * 256 + n2 * 128 + si * 64 + l];
        short8 bl = S[b][512 + BCH + wc * 256 + n2 * 128 + si * 64 + l];
        acc[n2][si] = __builtin_amdgcn_mfma_f32_32x32x16_bf16(ah, bh, acc[n2][si], 0, 0, 0);
        acc[n2][si] = __builtin_amdgcn_mfma_f32_32x32x16_bf16(al, bh, acc[n2][si], 0, 0, 0);
        acc[n2][si] = __builtin_amdgcn_mfma_f32_32x32x16_bf16(ah, bl, acc[n2][si], 0, 0, 0);
      }
    }
  }
#undef ZSTAGE

  int r0 = mb * 64 + wr * 32 + 4 * (l >> 5);
#pragma unroll
  for (int n2 = 0; n2 < NB; ++n2) {
    f32x16 a = acc[n2][0] + acc[n2][1];
    int colg = nbB * (NB * 64) + wc * 64 + n2 * 32 + (l & 31);
#pragma unroll
    for (int r = 0; r < 16; ++r) {
      int rowg = r0 + (r & 3) + 8 * (r >> 2);
      if (rowg < M) {
        float v = a[r];
        if (colg < 256) z1[(size_t)rowg * 256 + colg] = v;
        else            z2b[(size_t)rowg * 256 + colg - 256] = f2bh(v);
      }
    }
  }
}

// ===========================================================================
// h_build: h[i] = z1[i] + sum_{j in N(i)} z2[j] + c2.  2 nodes/block.
// ===========================================================================
__global__ __launch_bounds__(128) void h_build_kernel(
    const float* __restrict__ z1, const u16* __restrict__ z2b,
    const int* __restrict__ row, const int* __restrict__ col,
    const float* __restrict__ c2, float* __restrict__ h,
    u16* __restrict__ h_bf) {
  int i = blockIdx.x * 2 + (threadIdx.x >> 6);
  int t = threadIdx.x & 63;
  int half = t >> 5, sl = t & 31;
  int beg = row[i], end = row[i + 1];

  float a0[8] = {}, a1[8] = {}, a2[8] = {}, a3[8] = {};
  int e = beg + half;
  for (; e + 6 < end; e += 8) {
    int s0 = col[e], s1 = col[e + 2], s2 = col[e + 4], s3 = col[e + 6];
    short8 v0 = g16(z2b + (size_t)s0 * 256 + sl * 8);
    short8 v1 = g16(z2b + (size_t)s1 * 256 + sl * 8);
    short8 v2 = g16(z2b + (size_t)s2 * 256 + sl * 8);
    short8 v3 = g16(z2b + (size_t)s3 * 256 + sl * 8);
#pragma unroll
    for (int j = 0; j < 8; ++j) {
      a0[j] += bh2f((u16)v0[j]);
      a1[j] += bh2f((u16)v1[j]);
      a2[j] += bh2f((u16)v2[j]);
      a3[j] += bh2f((u16)v3[j]);
    }
  }
  for (; e < end; e += 2) {
    int s = col[e];
    short8 v = g16(z2b + (size_t)s * 256 + sl * 8);
#pragma unroll
    for (int j = 0; j < 8; ++j) a0[j] += bh2f((u16)v[j]);
  }
  float acc[8];
#pragma unroll
  for (int j = 0; j < 8; ++j) {
    acc[j] = a0[j] + a1[j] + a2[j] + a3[j];
    acc[j] += __shfl_xor(acc[j], 32);
  }
  float4 z1a = *reinterpret_cast<const float4*>(z1 + (size_t)i * 256 + sl * 8);
  float4 z1b = *reinterpret_cast<const float4*>(z1 + (size_t)i * 256 + sl * 8 + 4);
  float4 ca = *reinterpret_cast<const float4*>(c2 + sl * 8);
  float4 cb = *reinterpret_cast<const float4*>(c2 + sl * 8 + 4);
  float hv[8] = {z1a.x + ca.x + acc[0], z1a.y + ca.y + acc[1],
                 z1a.z + ca.z + acc[2], z1a.w + ca.w + acc[3],
                 z1b.x + cb.x + acc[4], z1b.y + cb.y + acc[5],
                 z1b.z + cb.z + acc[6], z1b.w + cb.w + acc[7]};
  if (half == 0) {
    float4 o0{hv[0], hv[1], hv[2], hv[3]};
    float4 o1{hv[4], hv[5], hv[6], hv[7]};
    *reinterpret_cast<float4*>(h + (size_t)i * 256 + sl * 8) = o0;
    *reinterpret_cast<float4*>(h + (size_t)i * 256 + sl * 8 + 4) = o1;
    short8 hb;
#pragma unroll
    for (int j = 0; j < 8; ++j) hb[j] = (short)f2bh(hv[j]);
    *reinterpret_cast<short8*>(h_bf + (size_t)i * 256 + sl * 8) = hb;
  }
}

// ===========================================================================
// GCN gather: out[i] = dis_i*sum dis_j h_j (bf16) + dis_i^2 h_i + b. 2 nodes/blk.
// ===========================================================================
__global__ __launch_bounds__(128) void gcn_gather_kernel(
    const float* __restrict__ h, const u16* __restrict__ h_bf,
    const int* __restrict__ row, const int* __restrict__ col,
    const float* __restrict__ dis, const float* __restrict__ gcn_b,
    float* __restrict__ outg) {
  int i = blockIdx.x * 2 + (threadIdx.x >> 6);
  int t = threadIdx.x & 63;
  int half = t >> 5, sl = t & 31;
  int beg = row[i], end = row[i + 1];
  float di = dis[i];

  float a0[8] = {}, a1[8] = {}, a2[8] = {}, a3[8] = {};
  int e = beg + half;
  for (; e + 6 < end; e += 8) {
    int s0 = col[e], s1 = col[e + 2], s2 = col[e + 4], s3 = col[e + 6];
    float w0 = dis[s0], w1 = dis[s1], w2 = dis[s2], w3 = dis[s3];
    short8 v0 = g16(h_bf + (size_t)s0 * 256 + sl * 8);
    short8 v1 = g16(h_bf + (size_t)s1 * 256 + sl * 8);
    short8 v2 = g16(h_bf + (size_t)s2 * 256 + sl * 8);
    short8 v3 = g16(h_bf + (size_t)s3 * 256 + sl * 8);
#pragma unroll
    for (int j = 0; j < 8; ++j) {
      a0[j] += w0 * bh2f((u16)v0[j]);
      a1[j] += w1 * bh2f((u16)v1[j]);
      a2[j] += w2 * bh2f((u16)v2[j]);
      a3[j] += w3 * bh2f((u16)v3[j]);
    }
  }
  for (; e < end; e += 2) {
    int s = col[e];
    float wv = dis[s];
    short8 v = g16(h_bf + (size_t)s * 256 + sl * 8);
#pragma unroll
    for (int j = 0; j < 8; ++j) a0[j] += wv * bh2f((u16)v[j]);
  }
  float acc[8];
#pragma unroll
  for (int j = 0; j < 8; ++j) {
    acc[j] = a0[j] + a1[j] + a2[j] + a3[j];
    acc[j] += __shfl_xor(acc[j], 32);
  }
  if (half == 0) {
    float4 ha = *reinterpret_cast<const float4*>(h + (size_t)i * 256 + sl * 8);
    float4 hb = *reinterpret_cast<const float4*>(h + (size_t)i * 256 + sl * 8 + 4);
    float4 ba = *reinterpret_cast<const float4*>(gcn_b + sl * 8);
    float4 bb = *reinterpret_cast<const float4*>(gcn_b + sl * 8 + 4);
    float self = di * di;
    float4 o0{di * acc[0] + self * ha.x + ba.x, di * acc[1] + self * ha.y + ba.y,
              di * acc[2] + self * ha.z + ba.z, di * acc[3] + self * ha.w + ba.w};
    float4 o1{di * acc[4] + self * hb.x + bb.x, di * acc[5] + self * hb.y + bb.y,
              di * acc[6] + self * hb.z + bb.z, di * acc[7] + self * hb.w + bb.w};
    *reinterpret_cast<float4*>(outg + (size_t)i * 256 + sl * 8) = o0;
    *reinterpret_cast<float4*>(outg + (size_t)i * 256 + sl * 8 + 4) = o1;
  }
}

// ===========================================================================
// decode MLP: 8 nodes per block
// ===========================================================================
#define DEC_NODES 8
__global__ __launch_bounds__(128) void decode_kernel(
    const float* __restrict__ outg, const float* __restrict__ d1_W,
    const float* __restrict__ d1_b, const float* __restrict__ d2_W,
    const float* __restrict__ d2_b, float* __restrict__ z1) {
  __shared__ float rows[DEC_NODES][OUT_DIM];
  __shared__ float s0[128], s1[128];
  int t = threadIdx.x;
  int n0 = blockIdx.x * DEC_NODES;
#pragma unroll
  for (int j = 0; j < 4; ++j) {
    int idx = j * 512 + t * 4;
    *reinterpret_cast<float4*>(&rows[0][idx]) =
        *reinterpret_cast<const float4*>(outg + (size_t)n0 * OUT_DIM + idx);
  }
  __syncthreads();
  float acc[DEC_NODES];
  float b1 = d1_b[t];
#pragma unroll
  for (int n = 0; n < DEC_NODES; ++n) acc[n] = b1;
#pragma unroll 4
  for (int k = 0; k < OUT_DIM; ++k) {
    float wv = d1_W[k * 128 + t];
#pragma unroll
    for (int n = 0; n < DEC_NODES; ++n) acc[n] += rows[n][k] * wv;
  }
  float w0 = d2_W[t * 2 + 0], w1 = d2_W[t * 2 + 1];
  for (int n = 0; n < DEC_NODES; ++n) {
    float a = fmaxf(acc[n], 0.f);
    s0[t] = a * w0;
    s1[t] = a * w1;
    __syncthreads();
    for (int off = 64; off > 0; off >>= 1) {
      if (t < off) {
        s0[t] += s0[t + off];
        s1[t] += s1[t + off];
      }
      __syncthreads();
    }
    if (t == 0) {
      z1[(size_t)(n0 + n) * 2 + 0] = s0[0] + d2_b[0];
      z1[(size_t)(n0 + n) * 2 + 1] = s1[0] + d2_b[1];
    }
    __syncthreads();
  }
}

// ===========================================================================
extern "C" void kernel_launch(void* const* d_in, const int* in_sizes, int n_in,
                              void* d_out, int out_size, void* d_ws, size_t ws_size,
                              hipStream_t stream) {
  const float* x     = (const float*)d_in[0];
  const int*   edge  = (const int*)d_in[1];
  const float* f_W   = (const float*)d_in[2];
  const float* f_b   = (const float*)d_in[3];
  const float* gcn_W = (const float*)d_in[4];
  const float* gcn_b = (const float*)d_in[5];
  const float* d1_W  = (const float*)d_in[6];
  const float* d1_b  = (const float*)d_in[7];
  const float* d2_W  = (const float*)d_in[8];
  const float* d2_b  = (const float*)d_in[9];
  float* out = (float*)d_out;
  char*  wsb = (char*)d_ws;

  const int* src = edge;
  const int* dst = edge + E_EDGES;

  // -------- layout (bytes) --------
  const size_t TS   = (size_t)MB_T * 16 * 256 * 8 * sizeof(u16);
  const size_t WTLE = (size_t)16 * 256 * 8 * sizeof(u16);

  size_t o = 0;
  u16*   x_hi = (u16*)(wsb + o); o += TS;
  u16*   x_lo = (u16*)(wsb + o); o += TS;
  float* z1   = (float*)(wsb + o); o += (size_t)N_NODES * 256 * 4;
  u16*   z2b  = (u16*)(wsb + o);   o += (size_t)N_NODES * 256 * 2;
  float* h    = (float*)(wsb + o); o += (size_t)N_NODES * 256 * 4;
  u16*   h_bf = (u16*)(wsb + o);   o += (size_t)N_NODES * 256 * 2;
  float* dis0 = (float*)(wsb + o); o += (size_t)N_NODES * 4;
  int*   icnt = (int*)(wsb + o);  o += (size_t)N_NODES * 4;
  float* c2   = (float*)(wsb + o); o += OUT_DIM * 4;   // adjacent to icnt
  int*   irow = (int*)(wsb + o);  o += (size_t)(N_NODES + 1) * 4 + 12;
  int*   icol = (int*)(wsb + o);  o += (size_t)E_EDGES * 4;
  u16*   Wcomb_hi = (u16*)(wsb + o); o += 8 * WTLE;
  u16*   Wcomb_lo = (u16*)(wsb + o); o += 8 * WTLE;
  u16*   WbotT_hi = (u16*)(wsb + o); o += 4 * WTLE;
  u16*   WbotT_lo = (u16*)(wsb + o); o += 4 * WTLE;
  u16*   fWp_hi   = (u16*)(wsb + o); o += 8 * WTLE;
  u16*   fWp_lo   = (u16*)(wsb + o); o += 8 * WTLE;
  float* outg = (float*)(wsb + 0);  // overlays x_hi (dead after Z-GEMM)
  const size_t needed = o;

  if (ws_size >= needed) {
    // ---- memset covers icnt + c2 (contiguous)
    hipMemsetAsync(icnt, 0, (size_t)N_NODES * sizeof(int) + OUT_DIM * sizeof(float), stream);

    // ---- fused prep (pack x, pack f_W, convT, c2, CSR count)
    prep_kernel<<<PREP_TOTAL, 256, 0, stream>>>(
        x, f_W, gcn_W, f_b, dst, icnt, x_hi, x_lo, fWp_hi, fWp_lo,
        Wcomb_hi, Wcomb_lo, WbotT_hi, WbotT_lo, c2);

    // ---- scan
    scan_kernel<<<1, 1024, 0, stream>>>(icnt, irow, dis0);

    // ---- fused place + W2 register GEMM
    pw_kernel<<<PW_TOTAL, 256, 0, stream>>>(
        src, dst, icnt, icol, WbotT_hi, WbotT_lo, fWp_hi, fWp_lo,
        Wcomb_hi, Wcomb_lo);

    // ---- Z = x @ [Wtop | W2] : z1 fp32, z2 bf16  (XCD-remapped)
    zgemm_kernel<2><<<640, 256, 0, stream>>>(
        x_hi, x_lo, Wcomb_hi, Wcomb_lo, z1, z2b, N_NODES, IN_DIM);

    // ---- h = z1 + gather(z2) + c2 (fp32 + bf16 shadow)
    h_build_kernel<<<N_NODES / 2, 128, 0, stream>>>(z1, z2b, irow, icol, c2, h, h_bf);

    // ---- GCN gather + decode
    gcn_gather_kernel<<<N_NODES / 2, 128, 0, stream>>>(h, h_bf, irow, icol, dis0, gcn_b, outg);
    decode_kernel<<<N_NODES / DEC_NODES, 128, 0, stream>>>(outg, d1_W, d1_b, d2_W, d2_b, out);
  }
}